// Round 8
// baseline (336.030 us; speedup 1.0000x reference)
//
#include <hip/hip_runtime.h>

// SepConv: out[b,c,i,j] = sum_{u,v} img[b,c,i+u,j+v] * vert[b,u,i,j] * hori[b,v,i,j]
// B=8, C=3, W=H=512, K=13, Wo=Ho=500.
//
// R8: BARRIER-FREE per-wave pipeline. Evidence R6/R7: block-wide staging
// barriers phase-lock HBM (burst/idle, <=2.1 TB/s) and small persistent
// blocks collapse wave count (R7: ~3 waves/CU). Here each wave owns one
// half-row task and its own private LDS slot:
//   - wave DMAs its 13KB vert slice via global_load_lds (no VGPR round-trip,
//     un-sinkable), waits only its own vmcnt — NO __syncthreads anywhere
//   - computes 3 channels with tmp[4][13] (R1 algebra), depth-1 img prefetch
//   - hori folded from 13 independent direct loads/channel (c=0 one cold
//     burst, c=1,2 L1 hits — same addresses)
// Waves cycle independently -> staggered stage/compute -> continuous HBM
// demand. LDS 6*13312=79872B -> 2 blocks/CU = 12 waves/CU.

#define KK 13
#define NB 8
#define NC 3
#define IW 512
#define IH 512
#define WO 500
#define HO 500
#define KHW 250000            // WO*HO
#define RS4 62500             // KHW/4: float4 stride between u-slices
#define QROW 125              // float4 quads per full 500-col row
#define NT 384                // 6 waves per block
#define WPB 6
#define SLOT (KK * 64)        // 832 float4 per wave slot
#define NTASK (NB * 2 * WO)   // 8000 half-row tasks
#define NBLK ((NTASK + WPB - 1) / WPB)   // 1334 blocks

typedef __attribute__((address_space(1))) const void g_void;
typedef __attribute__((address_space(3))) void l_void;

__global__ __launch_bounds__(NT) void sepconv_kernel(
    const float* __restrict__ img,
    const float* __restrict__ hori,
    const float* __restrict__ vert,
    float* __restrict__ out)
{
    __shared__ float4 smem[WPB * SLOT];   // 79872 B: one private slot per wave

    const int wave = threadIdx.x >> 6;
    const int lane = threadIdx.x & 63;
    const int W = blockIdx.x * WPB + wave;        // global wave id = task id
    if (W >= NTASK) return;                       // wave-uniform exit

    const unsigned bb   = (unsigned)W / 1000u;    // batch
    const unsigned rem  = (unsigned)W - bb * 1000u;
    const unsigned half = rem / 500u;             // which half-row
    const unsigned ii   = rem - half * 500u;      // output row
    const int q = (int)half * 64 + lane;          // j-quad index 0..124
    const bool valid = q < QROW;                  // half1: lanes 61..63 idle

    float4* slot = &smem[wave * SLOT];

    const float4* vsrc = (const float4*)(vert + (size_t)bb * KK * KHW + (size_t)ii * HO);
    const float4* hsrc = (const float4*)(hori + (size_t)bb * KK * KHW + (size_t)ii * HO);

    // ---- stage this wave's vert slice: 13 fire-and-forget DMA, own slot ----
    if (valid) {
        #pragma unroll
        for (int u = 0; u < KK; ++u)
            __builtin_amdgcn_global_load_lds(
                (g_void*)(vsrc + (size_t)u * RS4 + q),
                (l_void*)&slot[u * 64 + lane], 16, 0, 0);
    }
    // Drain own vmcnt only (no barrier): vmcnt(0), lgkm/exp ignored.
    __builtin_amdgcn_s_waitcnt(0x0f70);

    if (valid) {
        const int j0 = q * 4;

        #pragma unroll 1
        for (int c = 0; c < NC; ++c) {
            const float* ibase = img + (((size_t)(bb * NC + c) * IW) + ii) * IH + j0;

            float tmp[4][KK];
            #pragma unroll
            for (int jq = 0; jq < 4; ++jq)
                #pragma unroll
                for (int v = 0; v < KK; ++v)
                    tmp[jq][v] = 0.0f;

            float4 c0 = *(const float4*)(ibase + 0);
            float4 c1 = *(const float4*)(ibase + 4);
            float4 c2 = *(const float4*)(ibase + 8);
            float4 c3 = *(const float4*)(ibase + 12);

            #pragma unroll
            for (int u = 0; u < KK; ++u) {
                float4 n0, n1, n2, n3;
                if (u < KK - 1) {
                    const float* rp = ibase + (size_t)(u + 1) * IH;
                    n0 = *(const float4*)(rp + 0);
                    n1 = *(const float4*)(rp + 4);
                    n2 = *(const float4*)(rp + 8);
                    n3 = *(const float4*)(rp + 12);
                }

                const float4 vt = slot[u * 64 + lane];   // ds_read_b128, own slot

                float row[16];
                row[0]  = c0.x; row[1]  = c0.y; row[2]  = c0.z; row[3]  = c0.w;
                row[4]  = c1.x; row[5]  = c1.y; row[6]  = c1.z; row[7]  = c1.w;
                row[8]  = c2.x; row[9]  = c2.y; row[10] = c2.z; row[11] = c2.w;
                row[12] = c3.x; row[13] = c3.y; row[14] = c3.z; row[15] = c3.w;

                #pragma unroll
                for (int v = 0; v < KK; ++v) {
                    tmp[0][v] += row[0 + v] * vt.x;
                    tmp[1][v] += row[1 + v] * vt.y;
                    tmp[2][v] += row[2 + v] * vt.z;
                    tmp[3][v] += row[3 + v] * vt.w;
                }

                if (u < KK - 1) {
                    c0 = n0; c1 = n1; c2 = n2; c3 = n3;
                }
            }

            // epilogue: fold hori (13 independent loads; c=0 cold burst,
            // c=1,2 hit L1 at the same addresses)
            float4 o = make_float4(0.f, 0.f, 0.f, 0.f);
            #pragma unroll
            for (int v = 0; v < KK; ++v) {
                const float4 hv = hsrc[(size_t)v * RS4 + q];
                o.x += tmp[0][v] * hv.x;
                o.y += tmp[1][v] * hv.y;
                o.z += tmp[2][v] * hv.z;
                o.w += tmp[3][v] * hv.w;
            }

            float* op = out + (((size_t)(bb * NC + c) * WO) + ii) * HO + j0;
            *(float4*)op = o;
        }
    }
}

extern "C" void kernel_launch(void* const* d_in, const int* in_sizes, int n_in,
                              void* d_out, int out_size, void* d_ws, size_t ws_size,
                              hipStream_t stream) {
    const float* img  = (const float*)d_in[0];
    const float* hori = (const float*)d_in[1];
    const float* vert = (const float*)d_in[2];
    float* out = (float*)d_out;

    dim3 block(NT, 1, 1);         // 6 waves, one task each
    dim3 grid(NBLK, 1, 1);        // 1334 blocks = 8004 waves >= 8000 tasks
    hipLaunchKernelGGL(sepconv_kernel, grid, block, 0, stream, img, hori, vert, out);
}